// Round 1
// baseline (1369.479 us; speedup 1.0000x reference)
//
#include <hip/hip_runtime.h>
#include <math.h>

#define N_NODES 100000
#define N_EDGES 1600000
#define IN_FEAT 512
#define HIDDEN 64
#define N_CLASSES 40
#define N_LAYERS 6

// ---------------- graph preprocessing ----------------

__global__ void count_kernel(const int* __restrict__ dst, int* __restrict__ count) {
    int e = blockIdx.x * blockDim.x + threadIdx.x;
    if (e < N_EDGES) atomicAdd(&count[dst[e]], 1);
}

__global__ void dinv_kernel(const int* __restrict__ count, float* __restrict__ dinv) {
    int i = blockIdx.x * blockDim.x + threadIdx.x;
    if (i < N_NODES) dinv[i] = rsqrtf((float)(count[i] + 1));  // +1 self loop
}

// block-wise exclusive scan, 256 elements per block
__global__ void scan1_kernel(const int* __restrict__ count, int* __restrict__ row_start,
                             int* __restrict__ bsum) {
    __shared__ int sm[256];
    int t = threadIdx.x;
    int g = blockIdx.x * 256 + t;
    int v = (g < N_NODES) ? count[g] : 0;
    sm[t] = v;
    __syncthreads();
    int x = v;
    for (int off = 1; off < 256; off <<= 1) {
        int y = (t >= off) ? sm[t - off] : 0;
        __syncthreads();
        x += y;
        sm[t] = x;
        __syncthreads();
    }
    if (g < N_NODES) row_start[g] = x - v;  // exclusive within block
    if (t == 255) bsum[blockIdx.x] = x;     // block total
}

__global__ void scan2_kernel(int* __restrict__ bsum, int nb) {
    __shared__ int sm[512];
    int t = threadIdx.x;
    int v = (t < nb) ? bsum[t] : 0;
    sm[t] = v;
    __syncthreads();
    int x = v;
    for (int off = 1; off < 512; off <<= 1) {
        int y = (t >= off) ? sm[t - off] : 0;
        __syncthreads();
        x += y;
        sm[t] = x;
        __syncthreads();
    }
    if (t < nb) bsum[t] = x - v;  // exclusive block offsets
}

__global__ void scan3_kernel(int* __restrict__ row_start, const int* __restrict__ bsum) {
    int g = blockIdx.x * 256 + threadIdx.x;
    if (g < N_NODES) row_start[g] += bsum[blockIdx.x];
    if (g == 0) row_start[N_NODES] = N_EDGES;
}

__global__ void fill_kernel(const int* __restrict__ src, const int* __restrict__ dst,
                            const int* __restrict__ row_start, int* __restrict__ cursor,
                            const float* __restrict__ dinv, int* __restrict__ col,
                            float* __restrict__ wgt) {
    int e = blockIdx.x * blockDim.x + threadIdx.x;
    if (e < N_EDGES) {
        int s = src[e], d = dst[e];
        int p = row_start[d] + atomicAdd(&cursor[d], 1);
        col[p] = s;
        wgt[p] = dinv[s] * dinv[d];
    }
}

// ---------------- GEMM: C[M x 64] = A[M x K] @ W[K x 64] ----------------
// block: 256 threads, tile 64 rows x 64 cols, BK=32.

__global__ __launch_bounds__(256) void gemm_n64(const float* __restrict__ A,
                                                const float* __restrict__ W,
                                                float* __restrict__ C, int M, int K) {
    __shared__ float As[32][65];  // [k][row], pad 65 -> conflict-free transpose store
    __shared__ float Ws[32][64];  // [k][col]
    int t = threadIdx.x;
    int ty = t >> 4, tx = t & 15;
    int row0 = blockIdx.x * 64;
    float acc[4][4] = {};
    for (int k0 = 0; k0 < K; k0 += 32) {
        // A tile 64x32, coalesced float4 loads, transposed store
        #pragma unroll
        for (int i = 0; i < 2; i++) {
            int idx = t + i * 256;       // 0..511
            int r = idx >> 3, c4 = idx & 7;
            int gr = row0 + r;
            float4 v = make_float4(0.f, 0.f, 0.f, 0.f);
            if (gr < M) v = *(const float4*)(A + (size_t)gr * K + k0 + c4 * 4);
            As[c4 * 4 + 0][r] = v.x;
            As[c4 * 4 + 1][r] = v.y;
            As[c4 * 4 + 2][r] = v.z;
            As[c4 * 4 + 3][r] = v.w;
        }
        // W tile 32x64, direct float4
        #pragma unroll
        for (int i = 0; i < 2; i++) {
            int idx = t + i * 256;       // 0..511
            int r = idx >> 4, c4 = idx & 15;
            *(float4*)&Ws[r][c4 * 4] = *(const float4*)(W + (size_t)(k0 + r) * 64 + c4 * 4);
        }
        __syncthreads();
        #pragma unroll
        for (int k = 0; k < 32; k++) {
            float4 bv = *(float4*)&Ws[k][tx * 4];
            float av[4];
            #pragma unroll
            for (int i = 0; i < 4; i++) av[i] = As[k][ty * 4 + i];
            #pragma unroll
            for (int i = 0; i < 4; i++) {
                acc[i][0] += av[i] * bv.x;
                acc[i][1] += av[i] * bv.y;
                acc[i][2] += av[i] * bv.z;
                acc[i][3] += av[i] * bv.w;
            }
        }
        __syncthreads();
    }
    #pragma unroll
    for (int i = 0; i < 4; i++) {
        int gr = row0 + ty * 4 + i;
        if (gr < M) {
            float4 o = make_float4(acc[i][0], acc[i][1], acc[i][2], acc[i][3]);
            *(float4*)&C[(size_t)gr * 64 + tx * 4] = o;
        }
    }
}

// ---------------- aggregation + bias + relu + JK max ----------------
// one 64-lane wave per node; lane = feature

__global__ __launch_bounds__(256) void agg_kernel(const float* __restrict__ t,
                                                  const int* __restrict__ row_start,
                                                  const int* __restrict__ col,
                                                  const float* __restrict__ wgt,
                                                  const float* __restrict__ dinv,
                                                  const float* __restrict__ bias,
                                                  float* __restrict__ h_out,
                                                  float* __restrict__ jk, int first) {
    int node = (blockIdx.x * blockDim.x + threadIdx.x) >> 6;
    int lane = threadIdx.x & 63;
    if (node >= N_NODES) return;
    float di = dinv[node];
    float acc = t[(size_t)node * 64 + lane] * di * di;  // self loop
    int e0 = row_start[node], e1 = row_start[node + 1];
    int e = e0;
    if (e < e1) {
        int c = col[e];
        float w = wgt[e];
        for (; e + 1 < e1; ++e) {
            int cn = col[e + 1];          // prefetch next edge
            float wn = wgt[e + 1];
            acc += t[(size_t)c * 64 + lane] * w;
            c = cn; w = wn;
        }
        acc += t[(size_t)c * 64 + lane] * w;
    }
    float v = fmaxf(acc + bias[lane], 0.0f);
    h_out[(size_t)node * 64 + lane] = v;
    float* jp = jk + (size_t)node * 64 + lane;
    *jp = first ? v : fmaxf(*jp, v);
}

// ---------------- FC + log_softmax ----------------
// one wave per node; lanes 0..39 = classes

__global__ __launch_bounds__(256) void fc_kernel(const float* __restrict__ jk,
                                                 const float* __restrict__ fcW,
                                                 const float* __restrict__ fcb,
                                                 float* __restrict__ out) {
    __shared__ float Ws[64 * 40 + 64];  // padded so lane>=40 garbage reads stay in-bounds
    __shared__ float bs[40];
    int t = threadIdx.x;
    for (int i = t; i < 64 * 40 + 64; i += 256) Ws[i] = (i < 64 * 40) ? fcW[i] : 0.f;
    if (t < 40) bs[t] = fcb[t];
    __syncthreads();
    int node = (blockIdx.x * blockDim.x + t) >> 6;
    int lane = t & 63;
    if (node >= N_NODES) return;
    float x = jk[(size_t)node * 64 + lane];  // lane k holds feature k of the row
    float acc = (lane < N_CLASSES) ? bs[lane] : 0.f;
    #pragma unroll
    for (int k = 0; k < 64; k++) {
        float xv = __shfl(x, k, 64);
        acc += xv * Ws[k * 40 + lane];  // lanes>=40 compute garbage, masked below
    }
    float val = (lane < N_CLASSES) ? acc : -INFINITY;
    float m = val;
    #pragma unroll
    for (int off = 32; off; off >>= 1) m = fmaxf(m, __shfl_xor(m, off, 64));
    float ex = (lane < N_CLASSES) ? expf(val - m) : 0.0f;
    float ssum = ex;
    #pragma unroll
    for (int off = 32; off; off >>= 1) ssum += __shfl_xor(ssum, off, 64);
    if (lane < N_CLASSES) out[(size_t)node * N_CLASSES + lane] = val - m - logf(ssum);
}

// ---------------- launch ----------------

extern "C" void kernel_launch(void* const* d_in, const int* in_sizes, int n_in,
                              void* d_out, int out_size, void* d_ws, size_t ws_size,
                              hipStream_t stream) {
    const float* x      = (const float*)d_in[0];
    const int*   ei     = (const int*)d_in[1];
    const float* W0     = (const float*)d_in[2];
    const float* b0     = (const float*)d_in[3];
    const float* W_rest = (const float*)d_in[4];
    const float* b_rest = (const float*)d_in[5];
    const float* fcW    = (const float*)d_in[6];
    const float* fcb    = (const float*)d_in[7];
    float* out = (float*)d_out;

    const int* src = ei;
    const int* dst = ei + N_EDGES;

    char* w = (char*)d_ws;
    auto alloc = [&](size_t bytes) -> void* {
        void* p = (void*)w;
        w += (bytes + 255) / 256 * 256;
        return p;
    };
    int*   count     = (int*)alloc((size_t)N_NODES * 4);
    int*   cursor    = (int*)alloc((size_t)N_NODES * 4);
    int*   row_start = (int*)alloc((size_t)(N_NODES + 1) * 4);
    float* dinv      = (float*)alloc((size_t)N_NODES * 4);
    int*   col       = (int*)alloc((size_t)N_EDGES * 4);
    float* wgt       = (float*)alloc((size_t)N_EDGES * 4);
    int*   bsum      = (int*)alloc(512 * 4);
    float* bufA      = (float*)alloc((size_t)N_NODES * 64 * 4);
    float* bufB      = (float*)alloc((size_t)N_NODES * 64 * 4);
    float* jk        = (float*)alloc((size_t)N_NODES * 64 * 4);

    hipMemsetAsync(count, 0, (size_t)N_NODES * 4, stream);
    hipMemsetAsync(cursor, 0, (size_t)N_NODES * 4, stream);

    int ge = (N_EDGES + 255) / 256;
    int gn = (N_NODES + 255) / 256;  // 391
    count_kernel<<<ge, 256, 0, stream>>>(dst, count);
    dinv_kernel<<<gn, 256, 0, stream>>>(count, dinv);
    scan1_kernel<<<gn, 256, 0, stream>>>(count, row_start, bsum);
    scan2_kernel<<<1, 512, 0, stream>>>(bsum, gn);
    scan3_kernel<<<gn, 256, 0, stream>>>(row_start, bsum);
    fill_kernel<<<ge, 256, 0, stream>>>(src, dst, row_start, cursor, dinv, col, wgt);

    int g_gemm = (N_NODES + 63) / 64;
    int g_node = (N_NODES + 3) / 4;  // 4 waves/block

    gemm_n64<<<g_gemm, 256, 0, stream>>>(x, W0, bufA, N_NODES, IN_FEAT);
    agg_kernel<<<g_node, 256, 0, stream>>>(bufA, row_start, col, wgt, dinv, b0, bufB, jk, 1);
    for (int l = 1; l < N_LAYERS; l++) {
        gemm_n64<<<g_gemm, 256, 0, stream>>>(bufB, W_rest + (size_t)(l - 1) * 64 * 64, bufA,
                                             N_NODES, HIDDEN);
        agg_kernel<<<g_node, 256, 0, stream>>>(bufA, row_start, col, wgt, dinv,
                                               b_rest + (size_t)(l - 1) * 64, bufB, jk, 0);
    }
    fc_kernel<<<g_node, 256, 0, stream>>>(jk, fcW, fcb, out);
}

// Round 2
// 1202.419 us; speedup vs baseline: 1.1389x; 1.1389x over previous
//
#include <hip/hip_runtime.h>
#include <math.h>

#define N_NODES 100000
#define N_EDGES 1600000
#define IN_FEAT 512
#define HIDDEN 64
#define N_CLASSES 40
#define N_LAYERS 6

// ---------------- graph preprocessing ----------------

__global__ void count_kernel(const int* __restrict__ dst, int* __restrict__ count) {
    int e = blockIdx.x * blockDim.x + threadIdx.x;
    if (e < N_EDGES) atomicAdd(&count[dst[e]], 1);
}

__global__ void dinv_kernel(const int* __restrict__ count, float* __restrict__ dinv) {
    int i = blockIdx.x * blockDim.x + threadIdx.x;
    if (i < N_NODES) dinv[i] = rsqrtf((float)(count[i] + 1));  // +1 self loop
}

// block-wise exclusive scan, 256 elements per block
__global__ void scan1_kernel(const int* __restrict__ count, int* __restrict__ row_start,
                             int* __restrict__ bsum) {
    __shared__ int sm[256];
    int t = threadIdx.x;
    int g = blockIdx.x * 256 + t;
    int v = (g < N_NODES) ? count[g] : 0;
    sm[t] = v;
    __syncthreads();
    int x = v;
    for (int off = 1; off < 256; off <<= 1) {
        int y = (t >= off) ? sm[t - off] : 0;
        __syncthreads();
        x += y;
        sm[t] = x;
        __syncthreads();
    }
    if (g < N_NODES) row_start[g] = x - v;  // exclusive within block
    if (t == 255) bsum[blockIdx.x] = x;     // block total
}

__global__ void scan2_kernel(int* __restrict__ bsum, int nb) {
    __shared__ int sm[512];
    int t = threadIdx.x;
    int v = (t < nb) ? bsum[t] : 0;
    sm[t] = v;
    __syncthreads();
    int x = v;
    for (int off = 1; off < 512; off <<= 1) {
        int y = (t >= off) ? sm[t - off] : 0;
        __syncthreads();
        x += y;
        sm[t] = x;
        __syncthreads();
    }
    if (t < nb) bsum[t] = x - v;  // exclusive block offsets
}

__global__ void scan3_kernel(int* __restrict__ row_start, const int* __restrict__ bsum) {
    int g = blockIdx.x * 256 + threadIdx.x;
    if (g < N_NODES) row_start[g] += bsum[blockIdx.x];
    if (g == 0) row_start[N_NODES] = N_EDGES;
}

__global__ void fill_kernel(const int* __restrict__ src, const int* __restrict__ dst,
                            const int* __restrict__ row_start, int* __restrict__ cursor,
                            const float* __restrict__ dinv, int* __restrict__ col,
                            float* __restrict__ wgt) {
    int e = blockIdx.x * blockDim.x + threadIdx.x;
    if (e < N_EDGES) {
        int s = src[e], d = dst[e];
        int p = row_start[d] + atomicAdd(&cursor[d], 1);
        col[p] = s;
        wgt[p] = dinv[s] * dinv[d];
    }
}

// ---------------- GEMM: C[M x 64] = A[M x K] @ W[K x 64] ----------------
// block: 256 threads = 16x16; tile 128 rows x 64 cols, BK=32; 8x4 microtile.
// Inner loop: 32 FMA per thread per k against 3 b128 LDS reads -> VALU-bound.

__global__ __launch_bounds__(256) void gemm_tile(const float* __restrict__ A,
                                                 const float* __restrict__ W,
                                                 float* __restrict__ C, int M, int K) {
    __shared__ float As[32][132];  // [k][row], pad 128->132 (16B-aligned rows)
    __shared__ float Ws[32][64];   // [k][col]
    int t = threadIdx.x;
    int tx = t & 15;   // col group: cols tx*4 .. tx*4+3
    int ty = t >> 4;   // row group: rows ty*8 .. ty*8+7
    int row0 = blockIdx.x * 128;
    float acc[8][4] = {};
    for (int k0 = 0; k0 < K; k0 += 32) {
        // A tile 128x32: 1024 float4 loads, transposed store into As
        #pragma unroll
        for (int i = 0; i < 4; i++) {
            int idx = t + i * 256;       // 0..1023
            int r = idx >> 3;            // 0..127
            int c4 = idx & 7;            // 0..7
            int gr = row0 + r;
            float4 v = make_float4(0.f, 0.f, 0.f, 0.f);
            if (gr < M) v = *(const float4*)(A + (size_t)gr * K + k0 + c4 * 4);
            As[c4 * 4 + 0][r] = v.x;
            As[c4 * 4 + 1][r] = v.y;
            As[c4 * 4 + 2][r] = v.z;
            As[c4 * 4 + 3][r] = v.w;
        }
        // W tile 32x64: 512 float4 loads
        #pragma unroll
        for (int i = 0; i < 2; i++) {
            int idx = t + i * 256;       // 0..511
            int r = idx >> 4, c4 = idx & 15;
            *(float4*)&Ws[r][c4 * 4] = *(const float4*)(W + (size_t)(k0 + r) * 64 + c4 * 4);
        }
        __syncthreads();
        #pragma unroll
        for (int k = 0; k < 32; k++) {
            float4 bv = *(float4*)&Ws[k][tx * 4];
            float4 a0 = *(float4*)&As[k][ty * 8];
            float4 a1 = *(float4*)&As[k][ty * 8 + 4];
            float av[8] = {a0.x, a0.y, a0.z, a0.w, a1.x, a1.y, a1.z, a1.w};
            #pragma unroll
            for (int i = 0; i < 8; i++) {
                acc[i][0] += av[i] * bv.x;
                acc[i][1] += av[i] * bv.y;
                acc[i][2] += av[i] * bv.z;
                acc[i][3] += av[i] * bv.w;
            }
        }
        __syncthreads();
    }
    #pragma unroll
    for (int i = 0; i < 8; i++) {
        int gr = row0 + ty * 8 + i;
        if (gr < M) {
            float4 o = make_float4(acc[i][0], acc[i][1], acc[i][2], acc[i][3]);
            *(float4*)&C[(size_t)gr * 64 + tx * 4] = o;
        }
    }
}

// ---------------- aggregation + bias + relu + JK max ----------------
// one 64-lane wave per node; lane = feature; 4-deep unrolled gather for MLP;
// node scalarized so col/wgt become scalar (s_load) traffic.

__global__ __launch_bounds__(256) void agg_kernel(const float* __restrict__ t,
                                                  const int* __restrict__ row_start,
                                                  const int* __restrict__ col,
                                                  const float* __restrict__ wgt,
                                                  const float* __restrict__ dinv,
                                                  const float* __restrict__ bias,
                                                  float* __restrict__ h_out,
                                                  float* __restrict__ jk, int first) {
    int node = (blockIdx.x * blockDim.x + threadIdx.x) >> 6;
    int lane = threadIdx.x & 63;
    if (node >= N_NODES) return;
    node = __builtin_amdgcn_readfirstlane(node);  // wave-uniform -> SGPR
    float di = dinv[node];
    float acc = t[(size_t)node * 64 + lane] * di * di;  // self loop
    int e0 = row_start[node], e1 = row_start[node + 1];
    int e = e0;
    for (; e + 4 <= e1; e += 4) {
        int c0 = col[e], c1 = col[e + 1], c2 = col[e + 2], c3 = col[e + 3];
        float w0 = wgt[e], w1 = wgt[e + 1], w2 = wgt[e + 2], w3 = wgt[e + 3];
        float v0 = t[(size_t)c0 * 64 + lane];
        float v1 = t[(size_t)c1 * 64 + lane];
        float v2 = t[(size_t)c2 * 64 + lane];
        float v3 = t[(size_t)c3 * 64 + lane];
        acc += v0 * w0;
        acc += v1 * w1;
        acc += v2 * w2;
        acc += v3 * w3;
    }
    for (; e < e1; ++e) acc += t[(size_t)col[e] * 64 + lane] * wgt[e];
    float v = fmaxf(acc + bias[lane], 0.0f);
    h_out[(size_t)node * 64 + lane] = v;
    float* jp = jk + (size_t)node * 64 + lane;
    *jp = first ? v : fmaxf(*jp, v);
}

// ---------------- FC + log_softmax ----------------
// one wave per node; lanes 0..39 = classes

__global__ __launch_bounds__(256) void fc_kernel(const float* __restrict__ jk,
                                                 const float* __restrict__ fcW,
                                                 const float* __restrict__ fcb,
                                                 float* __restrict__ out) {
    __shared__ float Ws[64 * 40 + 64];  // padded so lane>=40 garbage reads stay in-bounds
    __shared__ float bs[40];
    int t = threadIdx.x;
    for (int i = t; i < 64 * 40 + 64; i += 256) Ws[i] = (i < 64 * 40) ? fcW[i] : 0.f;
    if (t < 40) bs[t] = fcb[t];
    __syncthreads();
    int node = (blockIdx.x * blockDim.x + t) >> 6;
    int lane = t & 63;
    if (node >= N_NODES) return;
    node = __builtin_amdgcn_readfirstlane(node);
    float x = jk[(size_t)node * 64 + lane];  // lane k holds feature k of the row
    float acc = (lane < N_CLASSES) ? bs[lane] : 0.f;
    #pragma unroll
    for (int k = 0; k < 64; k++) {
        float xv = __shfl(x, k, 64);
        acc += xv * Ws[k * 40 + lane];  // lanes>=40 compute garbage, masked below
    }
    float val = (lane < N_CLASSES) ? acc : -INFINITY;
    float m = val;
    #pragma unroll
    for (int off = 32; off; off >>= 1) m = fmaxf(m, __shfl_xor(m, off, 64));
    float ex = (lane < N_CLASSES) ? expf(val - m) : 0.0f;
    float ssum = ex;
    #pragma unroll
    for (int off = 32; off; off >>= 1) ssum += __shfl_xor(ssum, off, 64);
    if (lane < N_CLASSES) out[(size_t)node * N_CLASSES + lane] = val - m - logf(ssum);
}

// ---------------- launch ----------------

extern "C" void kernel_launch(void* const* d_in, const int* in_sizes, int n_in,
                              void* d_out, int out_size, void* d_ws, size_t ws_size,
                              hipStream_t stream) {
    const float* x      = (const float*)d_in[0];
    const int*   ei     = (const int*)d_in[1];
    const float* W0     = (const float*)d_in[2];
    const float* b0     = (const float*)d_in[3];
    const float* W_rest = (const float*)d_in[4];
    const float* b_rest = (const float*)d_in[5];
    const float* fcW    = (const float*)d_in[6];
    const float* fcb    = (const float*)d_in[7];
    float* out = (float*)d_out;

    const int* src = ei;
    const int* dst = ei + N_EDGES;

    char* w = (char*)d_ws;
    auto alloc = [&](size_t bytes) -> void* {
        void* p = (void*)w;
        w += (bytes + 255) / 256 * 256;
        return p;
    };
    int*   count     = (int*)alloc((size_t)N_NODES * 4);
    int*   cursor    = (int*)alloc((size_t)N_NODES * 4);
    int*   row_start = (int*)alloc((size_t)(N_NODES + 1) * 4);
    float* dinv      = (float*)alloc((size_t)N_NODES * 4);
    int*   col       = (int*)alloc((size_t)N_EDGES * 4);
    float* wgt       = (float*)alloc((size_t)N_EDGES * 4);
    int*   bsum      = (int*)alloc(512 * 4);
    float* bufA      = (float*)alloc((size_t)N_NODES * 64 * 4);
    float* bufB      = (float*)alloc((size_t)N_NODES * 64 * 4);
    float* jk        = (float*)alloc((size_t)N_NODES * 64 * 4);

    hipMemsetAsync(count, 0, (size_t)N_NODES * 4, stream);
    hipMemsetAsync(cursor, 0, (size_t)N_NODES * 4, stream);

    int ge = (N_EDGES + 255) / 256;
    int gn = (N_NODES + 255) / 256;  // 391
    count_kernel<<<ge, 256, 0, stream>>>(dst, count);
    dinv_kernel<<<gn, 256, 0, stream>>>(count, dinv);
    scan1_kernel<<<gn, 256, 0, stream>>>(count, row_start, bsum);
    scan2_kernel<<<1, 512, 0, stream>>>(bsum, gn);
    scan3_kernel<<<gn, 256, 0, stream>>>(row_start, bsum);
    fill_kernel<<<ge, 256, 0, stream>>>(src, dst, row_start, cursor, dinv, col, wgt);

    int g_gemm = (N_NODES + 127) / 128;  // 782
    int g_node = (N_NODES + 3) / 4;      // 4 waves/block

    gemm_tile<<<g_gemm, 256, 0, stream>>>(x, W0, bufA, N_NODES, IN_FEAT);
    agg_kernel<<<g_node, 256, 0, stream>>>(bufA, row_start, col, wgt, dinv, b0, bufB, jk, 1);
    for (int l = 1; l < N_LAYERS; l++) {
        gemm_tile<<<g_gemm, 256, 0, stream>>>(bufB, W_rest + (size_t)(l - 1) * 64 * 64, bufA,
                                              N_NODES, HIDDEN);
        agg_kernel<<<g_node, 256, 0, stream>>>(bufA, row_start, col, wgt, dinv,
                                               b_rest + (size_t)(l - 1) * 64, bufB, jk, 0);
    }
    fc_kernel<<<g_node, 256, 0, stream>>>(jk, fcW, fcb, out);
}

// Round 3
// 969.402 us; speedup vs baseline: 1.4127x; 1.2404x over previous
//
#include <hip/hip_runtime.h>
#include <math.h>

#define N_NODES 100000
#define N_EDGES 1600000
#define IN_FEAT 512
#define HIDDEN 64
#define N_CLASSES 40
#define N_LAYERS 6

typedef _Float16 v8h __attribute__((ext_vector_type(8)));
typedef _Float16 v4h __attribute__((ext_vector_type(4)));
typedef float v4f __attribute__((ext_vector_type(4)));

// ---------------- graph preprocessing ----------------

__global__ void count_kernel(const int* __restrict__ dst, int* __restrict__ count) {
    int e = blockIdx.x * blockDim.x + threadIdx.x;
    if (e < N_EDGES) atomicAdd(&count[dst[e]], 1);
}

__global__ void dinv_kernel(const int* __restrict__ count, float* __restrict__ dinv) {
    int i = blockIdx.x * blockDim.x + threadIdx.x;
    if (i < N_NODES) dinv[i] = rsqrtf((float)(count[i] + 1));  // +1 self loop
}

__global__ void scan1_kernel(const int* __restrict__ count, int* __restrict__ row_start,
                             int* __restrict__ bsum) {
    __shared__ int sm[256];
    int t = threadIdx.x;
    int g = blockIdx.x * 256 + t;
    int v = (g < N_NODES) ? count[g] : 0;
    sm[t] = v;
    __syncthreads();
    int x = v;
    for (int off = 1; off < 256; off <<= 1) {
        int y = (t >= off) ? sm[t - off] : 0;
        __syncthreads();
        x += y;
        sm[t] = x;
        __syncthreads();
    }
    if (g < N_NODES) row_start[g] = x - v;
    if (t == 255) bsum[blockIdx.x] = x;
}

__global__ void scan2_kernel(int* __restrict__ bsum, int nb) {
    __shared__ int sm[512];
    int t = threadIdx.x;
    int v = (t < nb) ? bsum[t] : 0;
    sm[t] = v;
    __syncthreads();
    int x = v;
    for (int off = 1; off < 512; off <<= 1) {
        int y = (t >= off) ? sm[t - off] : 0;
        __syncthreads();
        x += y;
        sm[t] = x;
        __syncthreads();
    }
    if (t < nb) bsum[t] = x - v;
}

__global__ void scan3_kernel(int* __restrict__ row_start, const int* __restrict__ bsum) {
    int g = blockIdx.x * 256 + threadIdx.x;
    if (g < N_NODES) row_start[g] += bsum[blockIdx.x];
    if (g == 0) row_start[N_NODES] = N_EDGES;
}

__global__ void fill_kernel(const int* __restrict__ src, const int* __restrict__ dst,
                            const int* __restrict__ row_start, int* __restrict__ cursor,
                            const float* __restrict__ dinv, int2* __restrict__ edge) {
    int e = blockIdx.x * blockDim.x + threadIdx.x;
    if (e < N_EDGES) {
        int s = src[e], d = dst[e];
        int p = row_start[d] + atomicAdd(&cursor[d], 1);
        edge[p] = make_int2(s, __float_as_int(dinv[s] * dinv[d]));
    }
}

// ---------------- weight prep: fp32 -> f16, transposed to [n][k] ----------------

__global__ void prep_w(const float* __restrict__ W0, const float* __restrict__ W_rest,
                       _Float16* __restrict__ Wt0, _Float16* __restrict__ Wtr) {
    int i = blockIdx.x * 256 + threadIdx.x;
    if (i < IN_FEAT * 64) {
        int k = i >> 6, n = i & 63;
        Wt0[n * IN_FEAT + k] = (_Float16)W0[i];
    }
    if (i < (N_LAYERS - 1) * 64 * 64) {
        int l = i >> 12, k = (i >> 6) & 63, n = i & 63;
        Wtr[l * 4096 + n * 64 + k] = (_Float16)W_rest[i];
    }
}

// ---------------- MFMA f16 GEMM: C[M x 64] (f16) = A[M x K] @ W[K x 64] ----------------
// Wt is W transposed, [64][K], f16. A is f16 ([M][K]) or fp32 when a_fp32 (layer 0: x).
// Block 256 = 4 waves; M-tile 64; wave w -> rows [w*16, w*16+16), 4 col tiles of 16.
// Frags (16x16x32 f16): A[m=lane&15][k=quad*8+j], B[k=quad*8+j][n=lane&15],
// D row = quad*4+reg, col = lane&15  [m89/m120 verified layouts]

__global__ __launch_bounds__(256) void gemm_mfma(const void* __restrict__ Ap, int a_fp32, int K,
                                                 const _Float16* __restrict__ Wt,
                                                 _Float16* __restrict__ C, int M) {
    __shared__ _Float16 As[64][32];  // [row][k], 64B rows -> b128-aligned frag reads
    __shared__ _Float16 Ws[64][32];  // [n][k] (Wt slice)
    int t = threadIdx.x;
    int lane = t & 63, w = t >> 6;
    int quad = lane >> 4, l15 = lane & 15;
    int m0 = blockIdx.x * 64;
    v4f acc[4];
    #pragma unroll
    for (int n = 0; n < 4; n++) acc[n] = (v4f){0.f, 0.f, 0.f, 0.f};

    for (int k0 = 0; k0 < K; k0 += 32) {
        if (a_fp32) {
            const float* A = (const float*)Ap;
            #pragma unroll
            for (int i = 0; i < 2; i++) {
                int idx = t + i * 256;        // 0..511
                int r = idx >> 3, seg = idx & 7;
                int gr = m0 + r;
                float4 v = make_float4(0.f, 0.f, 0.f, 0.f);
                if (gr < M) v = *(const float4*)(A + (size_t)gr * K + k0 + seg * 4);
                v4h h = {(_Float16)v.x, (_Float16)v.y, (_Float16)v.z, (_Float16)v.w};
                *(v4h*)&As[r][seg * 4] = h;
            }
        } else {
            const _Float16* A = (const _Float16*)Ap;
            int r = t >> 2, seg = t & 3;
            int gr = m0 + r;
            uint4 v = make_uint4(0u, 0u, 0u, 0u);
            if (gr < M) v = *(const uint4*)(A + (size_t)gr * K + k0 + seg * 8);
            *(uint4*)&As[r][seg * 8] = v;
        }
        {
            int r = t >> 2, seg = t & 3;
            *(uint4*)&Ws[r][seg * 8] = *(const uint4*)(Wt + (size_t)r * K + k0 + seg * 8);
        }
        __syncthreads();
        v8h a = *(v8h*)&As[w * 16 + l15][quad * 8];
        #pragma unroll
        for (int n = 0; n < 4; n++) {
            v8h b = *(v8h*)&Ws[n * 16 + l15][quad * 8];
            acc[n] = __builtin_amdgcn_mfma_f32_16x16x32_f16(a, b, acc[n], 0, 0, 0);
        }
        __syncthreads();
    }
    #pragma unroll
    for (int n = 0; n < 4; n++) {
        #pragma unroll
        for (int r = 0; r < 4; r++) {
            int gr = m0 + w * 16 + quad * 4 + r;
            if (gr < M) C[(size_t)gr * 64 + n * 16 + l15] = (_Float16)acc[n][r];
        }
    }
}

// ---------------- aggregation + bias + relu + JK max (f16 tables) ----------------
// one 64-lane wave per node; lane = feature; fp32 accumulate

__global__ __launch_bounds__(256) void agg_kernel(const _Float16* __restrict__ t,
                                                  const int* __restrict__ row_start,
                                                  const int2* __restrict__ edge,
                                                  const float* __restrict__ dinv,
                                                  const float* __restrict__ bias,
                                                  _Float16* __restrict__ h_out,
                                                  _Float16* __restrict__ jk, int first) {
    int node = (blockIdx.x * blockDim.x + threadIdx.x) >> 6;
    int lane = threadIdx.x & 63;
    if (node >= N_NODES) return;
    node = __builtin_amdgcn_readfirstlane(node);
    float di = dinv[node];
    float acc = (float)t[(size_t)node * 64 + lane] * di * di;  // self loop
    int e0 = row_start[node], e1 = row_start[node + 1];
    int e = e0;
    for (; e + 4 <= e1; e += 4) {
        int2 p0 = edge[e], p1 = edge[e + 1], p2 = edge[e + 2], p3 = edge[e + 3];
        float v0 = (float)t[(size_t)p0.x * 64 + lane];
        float v1 = (float)t[(size_t)p1.x * 64 + lane];
        float v2 = (float)t[(size_t)p2.x * 64 + lane];
        float v3 = (float)t[(size_t)p3.x * 64 + lane];
        acc += v0 * __int_as_float(p0.y);
        acc += v1 * __int_as_float(p1.y);
        acc += v2 * __int_as_float(p2.y);
        acc += v3 * __int_as_float(p3.y);
    }
    for (; e < e1; ++e) {
        int2 p = edge[e];
        acc += (float)t[(size_t)p.x * 64 + lane] * __int_as_float(p.y);
    }
    float v = fmaxf(acc + bias[lane], 0.0f);
    h_out[(size_t)node * 64 + lane] = (_Float16)v;
    _Float16* jp = jk + (size_t)node * 64 + lane;
    if (first) *jp = (_Float16)v;
    else {
        float o = (float)*jp;
        *jp = (_Float16)fmaxf(o, v);
    }
}

// ---------------- FC + log_softmax ----------------

__global__ __launch_bounds__(256) void fc_kernel(const _Float16* __restrict__ jk,
                                                 const float* __restrict__ fcW,
                                                 const float* __restrict__ fcb,
                                                 float* __restrict__ out) {
    __shared__ float Ws[64 * 40 + 64];
    __shared__ float bs[40];
    int t = threadIdx.x;
    for (int i = t; i < 64 * 40 + 64; i += 256) Ws[i] = (i < 64 * 40) ? fcW[i] : 0.f;
    if (t < 40) bs[t] = fcb[t];
    __syncthreads();
    int node = (blockIdx.x * blockDim.x + t) >> 6;
    int lane = t & 63;
    if (node >= N_NODES) return;
    node = __builtin_amdgcn_readfirstlane(node);
    float x = (float)jk[(size_t)node * 64 + lane];
    float acc = (lane < N_CLASSES) ? bs[lane] : 0.f;
    #pragma unroll
    for (int k = 0; k < 64; k++) {
        float xv = __shfl(x, k, 64);
        acc += xv * Ws[k * 40 + lane];
    }
    float val = (lane < N_CLASSES) ? acc : -INFINITY;
    float m = val;
    #pragma unroll
    for (int off = 32; off; off >>= 1) m = fmaxf(m, __shfl_xor(m, off, 64));
    float ex = (lane < N_CLASSES) ? expf(val - m) : 0.0f;
    float ssum = ex;
    #pragma unroll
    for (int off = 32; off; off >>= 1) ssum += __shfl_xor(ssum, off, 64);
    if (lane < N_CLASSES) out[(size_t)node * N_CLASSES + lane] = val - m - logf(ssum);
}

// ---------------- launch ----------------

extern "C" void kernel_launch(void* const* d_in, const int* in_sizes, int n_in,
                              void* d_out, int out_size, void* d_ws, size_t ws_size,
                              hipStream_t stream) {
    const float* x      = (const float*)d_in[0];
    const int*   ei     = (const int*)d_in[1];
    const float* W0     = (const float*)d_in[2];
    const float* b0     = (const float*)d_in[3];
    const float* W_rest = (const float*)d_in[4];
    const float* b_rest = (const float*)d_in[5];
    const float* fcW    = (const float*)d_in[6];
    const float* fcb    = (const float*)d_in[7];
    float* out = (float*)d_out;

    const int* src = ei;
    const int* dst = ei + N_EDGES;

    char* w = (char*)d_ws;
    auto alloc = [&](size_t bytes) -> void* {
        void* p = (void*)w;
        w += (bytes + 255) / 256 * 256;
        return p;
    };
    int*       count     = (int*)alloc((size_t)N_NODES * 4);
    int*       cursor    = (int*)alloc((size_t)N_NODES * 4);
    int*       row_start = (int*)alloc((size_t)(N_NODES + 1) * 4);
    float*     dinv      = (float*)alloc((size_t)N_NODES * 4);
    int2*      edge      = (int2*)alloc((size_t)N_EDGES * 8);
    int*       bsum      = (int*)alloc(512 * 4);
    _Float16*  bufA      = (_Float16*)alloc((size_t)N_NODES * 64 * 2);
    _Float16*  bufB      = (_Float16*)alloc((size_t)N_NODES * 64 * 2);
    _Float16*  jk        = (_Float16*)alloc((size_t)N_NODES * 64 * 2);
    _Float16*  Wt0       = (_Float16*)alloc((size_t)IN_FEAT * 64 * 2);
    _Float16*  Wtr       = (_Float16*)alloc((size_t)(N_LAYERS - 1) * 64 * 64 * 2);

    hipMemsetAsync(count, 0, (size_t)N_NODES * 4, stream);
    hipMemsetAsync(cursor, 0, (size_t)N_NODES * 4, stream);

    int ge = (N_EDGES + 255) / 256;
    int gn = (N_NODES + 255) / 256;  // 391
    count_kernel<<<ge, 256, 0, stream>>>(dst, count);
    dinv_kernel<<<gn, 256, 0, stream>>>(count, dinv);
    scan1_kernel<<<gn, 256, 0, stream>>>(count, row_start, bsum);
    scan2_kernel<<<1, 512, 0, stream>>>(bsum, gn);
    scan3_kernel<<<gn, 256, 0, stream>>>(row_start, bsum);
    fill_kernel<<<ge, 256, 0, stream>>>(src, dst, row_start, cursor, dinv, edge);
    prep_w<<<(IN_FEAT * 64 + 255) / 256, 256, 0, stream>>>(W0, W_rest, Wt0, Wtr);

    int g_gemm = (N_NODES + 63) / 64;  // 1563
    int g_node = (N_NODES + 3) / 4;    // 4 waves/block

    gemm_mfma<<<g_gemm, 256, 0, stream>>>(x, 1, IN_FEAT, Wt0, bufA, N_NODES);
    agg_kernel<<<g_node, 256, 0, stream>>>(bufA, row_start, edge, dinv, b0, bufB, jk, 1);
    for (int l = 1; l < N_LAYERS; l++) {
        gemm_mfma<<<g_gemm, 256, 0, stream>>>(bufB, 0, HIDDEN, Wtr + (size_t)(l - 1) * 4096,
                                              bufA, N_NODES);
        agg_kernel<<<g_node, 256, 0, stream>>>(bufA, row_start, edge, dinv,
                                               b_rest + (size_t)(l - 1) * 64, bufB, jk, 0);
    }
    fc_kernel<<<g_node, 256, 0, stream>>>(jk, fcW, fcb, out);
}

// Round 4
// 858.566 us; speedup vs baseline: 1.5951x; 1.1291x over previous
//
#include <hip/hip_runtime.h>
#include <math.h>

#define N_NODES 100000
#define N_EDGES 1600000
#define IN_FEAT 512
#define HIDDEN 64
#define N_CLASSES 40
#define N_LAYERS 6

typedef _Float16 v8h __attribute__((ext_vector_type(8)));
typedef _Float16 v4h __attribute__((ext_vector_type(4)));
typedef float v4f __attribute__((ext_vector_type(4)));

// ---------------- graph preprocessing ----------------

__global__ void count_kernel(const int* __restrict__ dst, int* __restrict__ count) {
    int e = blockIdx.x * blockDim.x + threadIdx.x;
    if (e < N_EDGES) atomicAdd(&count[dst[e]], 1);
}

__global__ void dinv_kernel(const int* __restrict__ count, float* __restrict__ dinv) {
    int i = blockIdx.x * blockDim.x + threadIdx.x;
    if (i < N_NODES) dinv[i] = rsqrtf((float)(count[i] + 1));  // +1 self loop
}

__global__ void scan1_kernel(const int* __restrict__ count, int* __restrict__ row_start,
                             int* __restrict__ bsum) {
    __shared__ int sm[256];
    int t = threadIdx.x;
    int g = blockIdx.x * 256 + t;
    int v = (g < N_NODES) ? count[g] : 0;
    sm[t] = v;
    __syncthreads();
    int x = v;
    for (int off = 1; off < 256; off <<= 1) {
        int y = (t >= off) ? sm[t - off] : 0;
        __syncthreads();
        x += y;
        sm[t] = x;
        __syncthreads();
    }
    if (g < N_NODES) row_start[g] = x - v;
    if (t == 255) bsum[blockIdx.x] = x;
}

__global__ void scan2_kernel(int* __restrict__ bsum, int nb) {
    __shared__ int sm[512];
    int t = threadIdx.x;
    int v = (t < nb) ? bsum[t] : 0;
    sm[t] = v;
    __syncthreads();
    int x = v;
    for (int off = 1; off < 512; off <<= 1) {
        int y = (t >= off) ? sm[t - off] : 0;
        __syncthreads();
        x += y;
        sm[t] = x;
        __syncthreads();
    }
    if (t < nb) bsum[t] = x - v;
}

__global__ void scan3_kernel(int* __restrict__ row_start, const int* __restrict__ bsum) {
    int g = blockIdx.x * 256 + threadIdx.x;
    if (g < N_NODES) row_start[g] += bsum[blockIdx.x];
    if (g == 0) row_start[N_NODES] = N_EDGES;
}

__global__ void fill_kernel(const int* __restrict__ src, const int* __restrict__ dst,
                            const int* __restrict__ row_start, int* __restrict__ cursor,
                            const float* __restrict__ dinv, int2* __restrict__ edge) {
    int e = blockIdx.x * blockDim.x + threadIdx.x;
    if (e < N_EDGES) {
        int s = src[e], d = dst[e];
        int p = row_start[d] + atomicAdd(&cursor[d], 1);
        edge[p] = make_int2(s, __float_as_int(dinv[s] * dinv[d]));
    }
}

// ---------------- weight prep: fp32 -> f16 transposed ----------------

__global__ void prep_w(const float* __restrict__ W0, const float* __restrict__ W_rest,
                       const float* __restrict__ fcW,
                       _Float16* __restrict__ Wt0, _Float16* __restrict__ Wtr,
                       _Float16* __restrict__ fcWt) {
    int i = blockIdx.x * 256 + threadIdx.x;
    if (i < IN_FEAT * 64) {
        int k = i >> 6, n = i & 63;
        Wt0[n * IN_FEAT + k] = (_Float16)W0[i];
    }
    if (i < (N_LAYERS - 1) * 64 * 64) {
        int l = i >> 12, k = (i >> 6) & 63, n = i & 63;
        Wtr[l * 4096 + n * 64 + k] = (_Float16)W_rest[i];
    }
    if (i < 48 * 64) {  // fcWt[n][k], pad n 40..47 with 0
        int n = i >> 6, k = i & 63;
        fcWt[i] = (n < N_CLASSES) ? (_Float16)fcW[k * N_CLASSES + n] : (_Float16)0.f;
    }
}

// ---------------- MFMA f16 GEMM: C[M x 64] (f16) = A[M x K] @ W[K x 64] ----------------
// LDS rows padded to 40 f16 (80 B, odd multiple of 16 B): frag b128 reads hit
// banks (r*20+quad*4)%32 -> 8 distinct 4-bank groups -> 2-way (free per m136).

#define LDP 40

__global__ __launch_bounds__(256) void gemm_mfma(const void* __restrict__ Ap, int a_fp32, int K,
                                                 const _Float16* __restrict__ Wt,
                                                 _Float16* __restrict__ C, int M) {
    __shared__ _Float16 As[64][LDP];
    __shared__ _Float16 Ws[64][LDP];
    int t = threadIdx.x;
    int lane = t & 63, w = t >> 6;
    int quad = lane >> 4, l15 = lane & 15;
    int m0 = blockIdx.x * 64;
    v4f acc[4];
    #pragma unroll
    for (int n = 0; n < 4; n++) acc[n] = (v4f){0.f, 0.f, 0.f, 0.f};

    for (int k0 = 0; k0 < K; k0 += 32) {
        if (a_fp32) {
            const float* A = (const float*)Ap;
            #pragma unroll
            for (int i = 0; i < 2; i++) {
                int idx = t + i * 256;        // 0..511
                int r = idx >> 3, seg = idx & 7;
                int gr = m0 + r;
                float4 v = make_float4(0.f, 0.f, 0.f, 0.f);
                if (gr < M) v = *(const float4*)(A + (size_t)gr * K + k0 + seg * 4);
                v4h h = {(_Float16)v.x, (_Float16)v.y, (_Float16)v.z, (_Float16)v.w};
                *(v4h*)&As[r][seg * 4] = h;
            }
        } else {
            const _Float16* A = (const _Float16*)Ap;
            int r = t >> 2, seg = t & 3;
            int gr = m0 + r;
            uint4 v = make_uint4(0u, 0u, 0u, 0u);
            if (gr < M) v = *(const uint4*)(A + (size_t)gr * K + k0 + seg * 8);
            *(uint4*)&As[r][seg * 8] = v;
        }
        {
            int r = t >> 2, seg = t & 3;
            *(uint4*)&Ws[r][seg * 8] = *(const uint4*)(Wt + (size_t)r * K + k0 + seg * 8);
        }
        __syncthreads();
        v8h a = *(v8h*)&As[w * 16 + l15][quad * 8];
        #pragma unroll
        for (int n = 0; n < 4; n++) {
            v8h b = *(v8h*)&Ws[n * 16 + l15][quad * 8];
            acc[n] = __builtin_amdgcn_mfma_f32_16x16x32_f16(a, b, acc[n], 0, 0, 0);
        }
        __syncthreads();
    }
    #pragma unroll
    for (int n = 0; n < 4; n++) {
        #pragma unroll
        for (int r = 0; r < 4; r++) {
            int gr = m0 + w * 16 + quad * 4 + r;
            if (gr < M) C[(size_t)gr * 64 + n * 16 + l15] = (_Float16)acc[n][r];
        }
    }
}

// ---------------- aggregation + bias + relu + JK max ----------------
// one wave per node; lane = g*16+j; group g gathers edge base+g's features
// j*4..j*4+3 as one dwordx2 (512 B per wave-instruction, 4 edges in flight),
// next-round edge data prefetched; self-loop is a virtual edge at index e1.

__global__ __launch_bounds__(256) void agg_kernel(const _Float16* __restrict__ tbl,
                                                  const int* __restrict__ row_start,
                                                  const int2* __restrict__ edge,
                                                  const float* __restrict__ dinv,
                                                  const float* __restrict__ bias,
                                                  _Float16* __restrict__ h_out,
                                                  _Float16* __restrict__ jk, int first) {
    int wid = (blockIdx.x * blockDim.x + threadIdx.x) >> 6;
    if (wid >= N_NODES) return;
    int node = __builtin_amdgcn_readfirstlane(wid);
    int lane = threadIdx.x & 63;
    int g = lane >> 4, j = lane & 15;
    const v4h* t4 = (const v4h*)tbl;
    float di = dinv[node];
    int e0 = row_start[node], e1 = row_start[node + 1];
    int e1p = e1 + 1;  // + virtual self edge
    float a0 = 0.f, a1 = 0.f, a2 = 0.f, a3 = 0.f;

    int e = e0 + g;
    int c; float wgt;
    if (e < e1) { int2 p = edge[e]; c = p.x; wgt = __int_as_float(p.y); }
    else { c = node; wgt = (e == e1) ? di * di : 0.0f; }

    for (int base = e0; base < e1p; base += 4) {
        int cn; float wn;
        int en = base + 4 + g;
        if (base + 4 < e1p) {
            if (en < e1) { int2 p = edge[en]; cn = p.x; wn = __int_as_float(p.y); }
            else { cn = node; wn = (en == e1) ? di * di : 0.0f; }
        } else { cn = node; wn = 0.0f; }
        v4h v = t4[(size_t)c * 16 + j];
        a0 += (float)v[0] * wgt;
        a1 += (float)v[1] * wgt;
        a2 += (float)v[2] * wgt;
        a3 += (float)v[3] * wgt;
        c = cn; wgt = wn;
    }
    // combine the 4 lane-groups
    a0 += __shfl_xor(a0, 16, 64); a0 += __shfl_xor(a0, 32, 64);
    a1 += __shfl_xor(a1, 16, 64); a1 += __shfl_xor(a1, 32, 64);
    a2 += __shfl_xor(a2, 16, 64); a2 += __shfl_xor(a2, 32, 64);
    a3 += __shfl_xor(a3, 16, 64); a3 += __shfl_xor(a3, 32, 64);

    if (g == 0) {
        float4 b4 = *(const float4*)&bias[j * 4];
        v4h hv;
        hv[0] = (_Float16)fmaxf(a0 + b4.x, 0.0f);
        hv[1] = (_Float16)fmaxf(a1 + b4.y, 0.0f);
        hv[2] = (_Float16)fmaxf(a2 + b4.z, 0.0f);
        hv[3] = (_Float16)fmaxf(a3 + b4.w, 0.0f);
        v4h* h4 = (v4h*)h_out;
        v4h* j4 = (v4h*)jk;
        size_t idx = (size_t)node * 16 + j;
        h4[idx] = hv;
        if (first) j4[idx] = hv;
        else {
            v4h o = j4[idx];
            #pragma unroll
            for (int i = 0; i < 4; i++) o[i] = (hv[i] > o[i]) ? hv[i] : o[i];
            j4[idx] = o;
        }
    }
}

// ---------------- FC + log_softmax via MFMA ----------------
// block 256 = 4 waves, M-tile 64 rows; N=48 (40 padded); K=64 (2 k-steps).

__global__ __launch_bounds__(256) void fc_mfma(const _Float16* __restrict__ jk,
                                               const _Float16* __restrict__ fcWt,
                                               const float* __restrict__ fcb,
                                               float* __restrict__ out, int M) {
    __shared__ _Float16 As[64][LDP];
    __shared__ _Float16 Ws[48][LDP];
    __shared__ float bs[48];
    int t = threadIdx.x;
    int lane = t & 63, w = t >> 6;
    int quad = lane >> 4, l15 = lane & 15;
    int m0 = blockIdx.x * 64;

    // stage A: 64 rows x 64 f16; two k-halves interleaved in LDS rows of 40:
    // keep full 64-k rows? rows are 40 wide -> store as two 32-k tiles stacked.
    // As[r][0..31] = k 0..31 handled per k-step below instead (restage).
    // Simpler: stage both halves into As and As2 via two passes per k-step.
    v4f acc[3];
    #pragma unroll
    for (int n = 0; n < 3; n++) acc[n] = (v4f){0.f, 0.f, 0.f, 0.f};

    if (t < 48) bs[t] = (t < N_CLASSES) ? fcb[t] : 0.0f;

    #pragma unroll
    for (int k0 = 0; k0 < 64; k0 += 32) {
        {
            int r = t >> 2, seg = t & 3;
            int gr = m0 + r;
            uint4 v = make_uint4(0u, 0u, 0u, 0u);
            if (gr < M) v = *(const uint4*)(jk + (size_t)gr * 64 + k0 + seg * 8);
            *(uint4*)&As[r][seg * 8] = v;
        }
        if (t < 192) {
            int r = t >> 2, seg = t & 3;
            *(uint4*)&Ws[r][seg * 8] = *(const uint4*)(fcWt + (size_t)r * 64 + k0 + seg * 8);
        }
        __syncthreads();
        v8h a = *(v8h*)&As[w * 16 + l15][quad * 8];
        #pragma unroll
        for (int n = 0; n < 3; n++) {
            v8h b = *(v8h*)&Ws[n * 16 + l15][quad * 8];
            acc[n] = __builtin_amdgcn_mfma_f32_16x16x32_f16(a, b, acc[n], 0, 0, 0);
        }
        __syncthreads();
    }

    // epilogue: rows w*16+quad*4+r, cols n*16+l15; log_softmax over cols 0..39
    float val[3][4];
    #pragma unroll
    for (int n = 0; n < 3; n++) {
        int col = n * 16 + l15;
        #pragma unroll
        for (int r = 0; r < 4; r++)
            val[n][r] = (col < N_CLASSES) ? acc[n][r] + bs[col] : -INFINITY;
    }
    #pragma unroll
    for (int r = 0; r < 4; r++) {
        float m = fmaxf(fmaxf(val[0][r], val[1][r]), val[2][r]);
        #pragma unroll
        for (int off = 8; off; off >>= 1) m = fmaxf(m, __shfl_xor(m, off, 64));
        float s = 0.f;
        #pragma unroll
        for (int n = 0; n < 3; n++)
            if (n * 16 + l15 < N_CLASSES) s += expf(val[n][r] - m);
        #pragma unroll
        for (int off = 8; off; off >>= 1) s += __shfl_xor(s, off, 64);
        float lse = m + logf(s);
        int gr = m0 + w * 16 + quad * 4 + r;
        if (gr < M) {
            #pragma unroll
            for (int n = 0; n < 3; n++) {
                int col = n * 16 + l15;
                if (col < N_CLASSES) out[(size_t)gr * N_CLASSES + col] = val[n][r] - lse;
            }
        }
    }
}

// ---------------- launch ----------------

extern "C" void kernel_launch(void* const* d_in, const int* in_sizes, int n_in,
                              void* d_out, int out_size, void* d_ws, size_t ws_size,
                              hipStream_t stream) {
    const float* x      = (const float*)d_in[0];
    const int*   ei     = (const int*)d_in[1];
    const float* W0     = (const float*)d_in[2];
    const float* b0     = (const float*)d_in[3];
    const float* W_rest = (const float*)d_in[4];
    const float* b_rest = (const float*)d_in[5];
    const float* fcW    = (const float*)d_in[6];
    const float* fcb    = (const float*)d_in[7];
    float* out = (float*)d_out;

    const int* src = ei;
    const int* dst = ei + N_EDGES;

    char* w = (char*)d_ws;
    auto alloc = [&](size_t bytes) -> void* {
        void* p = (void*)w;
        w += (bytes + 255) / 256 * 256;
        return p;
    };
    int*       count     = (int*)alloc((size_t)N_NODES * 4);
    int*       cursor    = (int*)alloc((size_t)N_NODES * 4);
    int*       row_start = (int*)alloc((size_t)(N_NODES + 1) * 4);
    float*     dinv      = (float*)alloc((size_t)N_NODES * 4);
    int2*      edge      = (int2*)alloc((size_t)N_EDGES * 8);
    int*       bsum      = (int*)alloc(512 * 4);
    _Float16*  bufA      = (_Float16*)alloc((size_t)N_NODES * 64 * 2);
    _Float16*  bufB      = (_Float16*)alloc((size_t)N_NODES * 64 * 2);
    _Float16*  jk        = (_Float16*)alloc((size_t)N_NODES * 64 * 2);
    _Float16*  Wt0       = (_Float16*)alloc((size_t)IN_FEAT * 64 * 2);
    _Float16*  Wtr       = (_Float16*)alloc((size_t)(N_LAYERS - 1) * 64 * 64 * 2);
    _Float16*  fcWt      = (_Float16*)alloc((size_t)48 * 64 * 2);

    hipMemsetAsync(count, 0, (size_t)N_NODES * 4, stream);
    hipMemsetAsync(cursor, 0, (size_t)N_NODES * 4, stream);

    int ge = (N_EDGES + 255) / 256;
    int gn = (N_NODES + 255) / 256;  // 391
    count_kernel<<<ge, 256, 0, stream>>>(dst, count);
    dinv_kernel<<<gn, 256, 0, stream>>>(count, dinv);
    scan1_kernel<<<gn, 256, 0, stream>>>(count, row_start, bsum);
    scan2_kernel<<<1, 512, 0, stream>>>(bsum, gn);
    scan3_kernel<<<gn, 256, 0, stream>>>(row_start, bsum);
    fill_kernel<<<ge, 256, 0, stream>>>(src, dst, row_start, cursor, dinv, edge);
    prep_w<<<(IN_FEAT * 64 + 255) / 256, 256, 0, stream>>>(W0, W_rest, fcW, Wt0, Wtr, fcWt);

    int g_gemm = (N_NODES + 63) / 64;  // 1563
    int g_node = (N_NODES + 3) / 4;    // 25000

    gemm_mfma<<<g_gemm, 256, 0, stream>>>(x, 1, IN_FEAT, Wt0, bufA, N_NODES);
    agg_kernel<<<g_node, 256, 0, stream>>>(bufA, row_start, edge, dinv, b0, bufB, jk, 1);
    for (int l = 1; l < N_LAYERS; l++) {
        gemm_mfma<<<g_gemm, 256, 0, stream>>>(bufB, 0, HIDDEN, Wtr + (size_t)(l - 1) * 4096,
                                              bufA, N_NODES);
        agg_kernel<<<g_node, 256, 0, stream>>>(bufA, row_start, edge, dinv,
                                               b_rest + (size_t)(l - 1) * 64, bufB, jk, 0);
    }
    fc_mfma<<<g_gemm, 256, 0, stream>>>(jk, fcWt, fcb, out, N_NODES);
}

// Round 5
// 820.699 us; speedup vs baseline: 1.6687x; 1.0461x over previous
//
#include <hip/hip_runtime.h>
#include <math.h>

#define N_NODES 100000
#define N_EDGES 1600000
#define IN_FEAT 512
#define HIDDEN 64
#define N_CLASSES 40
#define N_LAYERS 6

typedef _Float16 v8h __attribute__((ext_vector_type(8)));
typedef _Float16 v4h __attribute__((ext_vector_type(4)));
typedef float v4f __attribute__((ext_vector_type(4)));

// ---------------- graph preprocessing ----------------

__global__ void count_kernel(const int* __restrict__ dst, int* __restrict__ count) {
    int e = blockIdx.x * blockDim.x + threadIdx.x;
    if (e < N_EDGES) atomicAdd(&count[dst[e]], 1);
}

__global__ void dinv_kernel(const int* __restrict__ count, float* __restrict__ dinv) {
    int i = blockIdx.x * blockDim.x + threadIdx.x;
    if (i < N_NODES) dinv[i] = rsqrtf((float)(count[i] + 1));  // +1 self loop
}

__global__ void scan1_kernel(const int* __restrict__ count, int* __restrict__ row_start,
                             int* __restrict__ bsum) {
    __shared__ int sm[256];
    int t = threadIdx.x;
    int g = blockIdx.x * 256 + t;
    int v = (g < N_NODES) ? count[g] : 0;
    sm[t] = v;
    __syncthreads();
    int x = v;
    for (int off = 1; off < 256; off <<= 1) {
        int y = (t >= off) ? sm[t - off] : 0;
        __syncthreads();
        x += y;
        sm[t] = x;
        __syncthreads();
    }
    if (g < N_NODES) row_start[g] = x - v;
    if (t == 255) bsum[blockIdx.x] = x;
}

__global__ void scan2_kernel(int* __restrict__ bsum, int nb) {
    __shared__ int sm[512];
    int t = threadIdx.x;
    int v = (t < nb) ? bsum[t] : 0;
    sm[t] = v;
    __syncthreads();
    int x = v;
    for (int off = 1; off < 512; off <<= 1) {
        int y = (t >= off) ? sm[t - off] : 0;
        __syncthreads();
        x += y;
        sm[t] = x;
        __syncthreads();
    }
    if (t < nb) bsum[t] = x - v;
}

__global__ void scan3_kernel(int* __restrict__ row_start, const int* __restrict__ bsum) {
    int g = blockIdx.x * 256 + threadIdx.x;
    if (g < N_NODES) row_start[g] += bsum[blockIdx.x];
    if (g == 0) row_start[N_NODES] = N_EDGES;
}

__global__ void fill_kernel(const int* __restrict__ src, const int* __restrict__ dst,
                            const int* __restrict__ row_start, int* __restrict__ cursor,
                            const float* __restrict__ dinv, int2* __restrict__ edge) {
    int e = blockIdx.x * blockDim.x + threadIdx.x;
    if (e < N_EDGES) {
        int s = src[e], d = dst[e];
        int p = row_start[d] + atomicAdd(&cursor[d], 1);
        edge[p] = make_int2(s, __float_as_int(dinv[s] * dinv[d]));
    }
}

// ---------------- weight prep: fp32 -> f16 transposed ----------------

__global__ void prep_w(const float* __restrict__ W0, const float* __restrict__ W_rest,
                       const float* __restrict__ fcW,
                       _Float16* __restrict__ Wt0, _Float16* __restrict__ Wtr,
                       _Float16* __restrict__ fcWt) {
    int i = blockIdx.x * 256 + threadIdx.x;
    if (i < IN_FEAT * 64) {
        int k = i >> 6, n = i & 63;
        Wt0[n * IN_FEAT + k] = (_Float16)W0[i];
    }
    if (i < (N_LAYERS - 1) * 64 * 64) {
        int l = i >> 12, k = (i >> 6) & 63, n = i & 63;
        Wtr[l * 4096 + n * 64 + k] = (_Float16)W_rest[i];
    }
    if (i < 48 * 64) {  // fcWt[n][k], pad n 40..47 with 0
        int n = i >> 6, k = i & 63;
        fcWt[i] = (n < N_CLASSES) ? (_Float16)fcW[k * N_CLASSES + n] : (_Float16)0.f;
    }
}

// ---------------- MFMA f16 GEMM: C[M x 64] (f16) = A[M x K] @ W[K x 64] ----------------
// M-tile 128, 4 waves, wave w -> row-tiles w*32 and w*32+16; LDS rows padded to
// 40 f16 (80 B, odd x16B): frag b128 reads are 2-way bank aliased = free (m136).

#define LDP 40

__global__ __launch_bounds__(256) void gemm_mfma(const void* __restrict__ Ap, int a_fp32, int K,
                                                 const _Float16* __restrict__ Wt,
                                                 _Float16* __restrict__ C, int M) {
    __shared__ _Float16 As[128][LDP];
    __shared__ _Float16 Ws[64][LDP];
    int t = threadIdx.x;
    int lane = t & 63, w = t >> 6;
    int quad = lane >> 4, l15 = lane & 15;
    int m0 = blockIdx.x * 128;
    v4f acc[2][4];
    #pragma unroll
    for (int u = 0; u < 2; u++)
        #pragma unroll
        for (int n = 0; n < 4; n++) acc[u][n] = (v4f){0.f, 0.f, 0.f, 0.f};

    for (int k0 = 0; k0 < K; k0 += 32) {
        if (a_fp32) {
            const float* A = (const float*)Ap;
            #pragma unroll
            for (int i = 0; i < 4; i++) {
                int idx = t + i * 256;        // 0..1023
                int r = idx >> 3, seg = idx & 7;
                int gr = m0 + r;
                float4 v = make_float4(0.f, 0.f, 0.f, 0.f);
                if (gr < M) v = *(const float4*)(A + (size_t)gr * K + k0 + seg * 4);
                v4h h = {(_Float16)v.x, (_Float16)v.y, (_Float16)v.z, (_Float16)v.w};
                *(v4h*)&As[r][seg * 4] = h;
            }
        } else {
            const _Float16* A = (const _Float16*)Ap;
            #pragma unroll
            for (int i = 0; i < 2; i++) {
                int idx = t + i * 256;        // 0..511
                int r = idx >> 2, seg = idx & 3;
                int gr = m0 + r;
                uint4 v = make_uint4(0u, 0u, 0u, 0u);
                if (gr < M) v = *(const uint4*)(A + (size_t)gr * K + k0 + seg * 8);
                *(uint4*)&As[r][seg * 8] = v;
            }
        }
        {
            int r = t >> 2, seg = t & 3;
            *(uint4*)&Ws[r][seg * 8] = *(const uint4*)(Wt + (size_t)r * K + k0 + seg * 8);
        }
        __syncthreads();
        v8h a0 = *(v8h*)&As[w * 32 + l15][quad * 8];
        v8h a1 = *(v8h*)&As[w * 32 + 16 + l15][quad * 8];
        #pragma unroll
        for (int n = 0; n < 4; n++) {
            v8h b = *(v8h*)&Ws[n * 16 + l15][quad * 8];
            acc[0][n] = __builtin_amdgcn_mfma_f32_16x16x32_f16(a0, b, acc[0][n], 0, 0, 0);
            acc[1][n] = __builtin_amdgcn_mfma_f32_16x16x32_f16(a1, b, acc[1][n], 0, 0, 0);
        }
        __syncthreads();
    }
    #pragma unroll
    for (int u = 0; u < 2; u++)
        #pragma unroll
        for (int n = 0; n < 4; n++)
            #pragma unroll
            for (int r = 0; r < 4; r++) {
                int gr = m0 + w * 32 + u * 16 + quad * 4 + r;
                if (gr < M) C[(size_t)gr * 64 + n * 16 + l15] = (_Float16)acc[u][n][r];
            }
}

// ---------------- aggregation + bias + relu + JK max ----------------
// one wave per node; lane = g*8+j: group g takes edge base+g, lane loads a b128
// (8 f16 feats) -> 8 edges per gather instruction, ~2-3 dependent rounds/node.
// Self-loop = weight-masked pre-gather (overlaps round 0). Combine groups via
// 3x shfl_xor; group 0 writes b128.

__global__ __launch_bounds__(256) void agg_kernel(const _Float16* __restrict__ tbl,
                                                  const int* __restrict__ row_start,
                                                  const int2* __restrict__ edge,
                                                  const float* __restrict__ dinv,
                                                  const float* __restrict__ bias,
                                                  _Float16* __restrict__ h_out,
                                                  _Float16* __restrict__ jk, int first) {
    int wid = (blockIdx.x * blockDim.x + threadIdx.x) >> 6;
    if (wid >= N_NODES) return;
    int node = __builtin_amdgcn_readfirstlane(wid);
    int lane = threadIdx.x & 63;
    int g = lane >> 3, j = lane & 7;
    const v8h* t8 = (const v8h*)tbl;
    float di = dinv[node];
    int e0 = row_start[node], e1 = row_start[node + 1];

    float a[8];
    // self loop: all lanes gather node's row (one line, 8-way broadcast);
    // weight masked to group 0 only
    {
        v8h v = t8[(size_t)node * 8 + j];
        float ws = (g == 0) ? di * di : 0.f;
        #pragma unroll
        for (int i = 0; i < 8; i++) a[i] = (float)v[i] * ws;
    }
    // pipelined edge loop, 8 edges per round
    int e = e0 + g;
    int c = node; float wgt = 0.f;
    if (e < e1) { int2 p = edge[e]; c = p.x; wgt = __int_as_float(p.y); }
    for (int base = e0; base < e1; base += 8) {
        int cn = node; float wn = 0.f;
        int en = base + 8 + g;
        if (en < e1) { int2 p = edge[en]; cn = p.x; wn = __int_as_float(p.y); }
        v8h v = t8[(size_t)c * 8 + j];
        #pragma unroll
        for (int i = 0; i < 8; i++) a[i] += (float)v[i] * wgt;
        c = cn; wgt = wn;
    }
    // combine the 8 lane-groups (xor over g bits 3,4,5)
    #pragma unroll
    for (int i = 0; i < 8; i++) {
        a[i] += __shfl_xor(a[i], 8, 64);
        a[i] += __shfl_xor(a[i], 16, 64);
        a[i] += __shfl_xor(a[i], 32, 64);
    }
    if (g == 0) {
        const float4* b4 = (const float4*)bias;
        float4 b0 = b4[j * 2], b1 = b4[j * 2 + 1];
        float bb[8] = {b0.x, b0.y, b0.z, b0.w, b1.x, b1.y, b1.z, b1.w};
        v8h hv;
        #pragma unroll
        for (int i = 0; i < 8; i++) hv[i] = (_Float16)fmaxf(a[i] + bb[i], 0.0f);
        v8h* h8 = (v8h*)h_out;
        v8h* j8 = (v8h*)jk;
        size_t idx = (size_t)node * 8 + j;
        h8[idx] = hv;
        if (first) j8[idx] = hv;
        else {
            v8h o = j8[idx];
            #pragma unroll
            for (int i = 0; i < 8; i++) o[i] = (hv[i] > o[i]) ? hv[i] : o[i];
            j8[idx] = o;
        }
    }
}

// ---------------- FC + log_softmax via MFMA ----------------
// block 256 = 4 waves, M-tile 64 rows; N=48 (40 padded); K=64 (2 k-steps).

__global__ __launch_bounds__(256) void fc_mfma(const _Float16* __restrict__ jk,
                                               const _Float16* __restrict__ fcWt,
                                               const float* __restrict__ fcb,
                                               float* __restrict__ out, int M) {
    __shared__ _Float16 As[64][LDP];
    __shared__ _Float16 Ws[48][LDP];
    __shared__ float bs[48];
    int t = threadIdx.x;
    int lane = t & 63, w = t >> 6;
    int quad = lane >> 4, l15 = lane & 15;
    int m0 = blockIdx.x * 64;

    v4f acc[3];
    #pragma unroll
    for (int n = 0; n < 3; n++) acc[n] = (v4f){0.f, 0.f, 0.f, 0.f};

    if (t < 48) bs[t] = (t < N_CLASSES) ? fcb[t] : 0.0f;

    #pragma unroll
    for (int k0 = 0; k0 < 64; k0 += 32) {
        {
            int r = t >> 2, seg = t & 3;
            int gr = m0 + r;
            uint4 v = make_uint4(0u, 0u, 0u, 0u);
            if (gr < M) v = *(const uint4*)(jk + (size_t)gr * 64 + k0 + seg * 8);
            *(uint4*)&As[r][seg * 8] = v;
        }
        if (t < 192) {
            int r = t >> 2, seg = t & 3;
            *(uint4*)&Ws[r][seg * 8] = *(const uint4*)(fcWt + (size_t)r * 64 + k0 + seg * 8);
        }
        __syncthreads();
        v8h a = *(v8h*)&As[w * 16 + l15][quad * 8];
        #pragma unroll
        for (int n = 0; n < 3; n++) {
            v8h b = *(v8h*)&Ws[n * 16 + l15][quad * 8];
            acc[n] = __builtin_amdgcn_mfma_f32_16x16x32_f16(a, b, acc[n], 0, 0, 0);
        }
        __syncthreads();
    }

    float val[3][4];
    #pragma unroll
    for (int n = 0; n < 3; n++) {
        int col = n * 16 + l15;
        #pragma unroll
        for (int r = 0; r < 4; r++)
            val[n][r] = (col < N_CLASSES) ? acc[n][r] + bs[col] : -INFINITY;
    }
    #pragma unroll
    for (int r = 0; r < 4; r++) {
        float m = fmaxf(fmaxf(val[0][r], val[1][r]), val[2][r]);
        #pragma unroll
        for (int off = 8; off; off >>= 1) m = fmaxf(m, __shfl_xor(m, off, 64));
        float s = 0.f;
        #pragma unroll
        for (int n = 0; n < 3; n++)
            if (n * 16 + l15 < N_CLASSES) s += expf(val[n][r] - m);
        #pragma unroll
        for (int off = 8; off; off >>= 1) s += __shfl_xor(s, off, 64);
        float lse = m + logf(s);
        int gr = m0 + w * 16 + quad * 4 + r;
        if (gr < M) {
            #pragma unroll
            for (int n = 0; n < 3; n++) {
                int col = n * 16 + l15;
                if (col < N_CLASSES) out[(size_t)gr * N_CLASSES + col] = val[n][r] - lse;
            }
        }
    }
}

// ---------------- launch ----------------

extern "C" void kernel_launch(void* const* d_in, const int* in_sizes, int n_in,
                              void* d_out, int out_size, void* d_ws, size_t ws_size,
                              hipStream_t stream) {
    const float* x      = (const float*)d_in[0];
    const int*   ei     = (const int*)d_in[1];
    const float* W0     = (const float*)d_in[2];
    const float* b0     = (const float*)d_in[3];
    const float* W_rest = (const float*)d_in[4];
    const float* b_rest = (const float*)d_in[5];
    const float* fcW    = (const float*)d_in[6];
    const float* fcb    = (const float*)d_in[7];
    float* out = (float*)d_out;

    const int* src = ei;
    const int* dst = ei + N_EDGES;

    char* w = (char*)d_ws;
    auto alloc = [&](size_t bytes) -> void* {
        void* p = (void*)w;
        w += (bytes + 255) / 256 * 256;
        return p;
    };
    int*       count     = (int*)alloc((size_t)N_NODES * 4);
    int*       cursor    = (int*)alloc((size_t)N_NODES * 4);
    int*       row_start = (int*)alloc((size_t)(N_NODES + 1) * 4);
    float*     dinv      = (float*)alloc((size_t)N_NODES * 4);
    int2*      edge      = (int2*)alloc((size_t)N_EDGES * 8);
    int*       bsum      = (int*)alloc(512 * 4);
    _Float16*  bufA      = (_Float16*)alloc((size_t)N_NODES * 64 * 2);
    _Float16*  bufB      = (_Float16*)alloc((size_t)N_NODES * 64 * 2);
    _Float16*  jk        = (_Float16*)alloc((size_t)N_NODES * 64 * 2);
    _Float16*  Wt0       = (_Float16*)alloc((size_t)IN_FEAT * 64 * 2);
    _Float16*  Wtr       = (_Float16*)alloc((size_t)(N_LAYERS - 1) * 64 * 64 * 2);
    _Float16*  fcWt      = (_Float16*)alloc((size_t)48 * 64 * 2);

    hipMemsetAsync(count, 0, (size_t)N_NODES * 4, stream);
    hipMemsetAsync(cursor, 0, (size_t)N_NODES * 4, stream);

    int ge = (N_EDGES + 255) / 256;
    int gn = (N_NODES + 255) / 256;  // 391
    count_kernel<<<ge, 256, 0, stream>>>(dst, count);
    dinv_kernel<<<gn, 256, 0, stream>>>(count, dinv);
    scan1_kernel<<<gn, 256, 0, stream>>>(count, row_start, bsum);
    scan2_kernel<<<1, 512, 0, stream>>>(bsum, gn);
    scan3_kernel<<<gn, 256, 0, stream>>>(row_start, bsum);
    fill_kernel<<<ge, 256, 0, stream>>>(src, dst, row_start, cursor, dinv, edge);
    prep_w<<<(IN_FEAT * 64 + 255) / 256, 256, 0, stream>>>(W0, W_rest, fcW, Wt0, Wtr, fcWt);

    int g_gemm = (N_NODES + 127) / 128;  // 782
    int g_fc   = (N_NODES + 63) / 64;    // 1563
    int g_node = (N_NODES + 3) / 4;      // 25000

    gemm_mfma<<<g_gemm, 256, 0, stream>>>(x, 1, IN_FEAT, Wt0, bufA, N_NODES);
    agg_kernel<<<g_node, 256, 0, stream>>>(bufA, row_start, edge, dinv, b0, bufB, jk, 1);
    for (int l = 1; l < N_LAYERS; l++) {
        gemm_mfma<<<g_gemm, 256, 0, stream>>>(bufB, 0, HIDDEN, Wtr + (size_t)(l - 1) * 4096,
                                              bufA, N_NODES);
        agg_kernel<<<g_node, 256, 0, stream>>>(bufA, row_start, edge, dinv,
                                               b_rest + (size_t)(l - 1) * 64, bufB, jk, 0);
    }
    fc_mfma<<<g_fc, 256, 0, stream>>>(jk, fcWt, fcb, out, N_NODES);
}